// Round 6
// baseline (4391.384 us; speedup 1.0000x reference)
//
#include <hip/hip_runtime.h>
#include <hip/hip_bf16.h>
#include <hip/hip_fp16.h>

typedef _Float16 f16;
typedef _Float16 f16x8 __attribute__((ext_vector_type(8)));
typedef float f32x4 __attribute__((ext_vector_type(4)));
typedef unsigned int u32;
typedef unsigned long long u64;

#define HB 2048
#define DD 2048
#define TT 256
#define BB 64
#define CWG 64  // persistent WGs (32 cols each)

typedef const __attribute__((address_space(1))) u32 gu32;
typedef __attribute__((address_space(3))) u32 lu32;

__device__ __forceinline__ void gl_lds16(const void* g, void* l) {
    __builtin_amdgcn_global_load_lds((gu32*)g, (lu32*)l, 16, 0, 0);
}

// ---------- transpose + convert fp32 [R][C] -> fp16 [C][R] (square 2048) ----------
__global__ __launch_bounds__(256) void k_transpose_cvt(const float* __restrict__ src,
                                                       f16* __restrict__ dst) {
    __shared__ f16 tile[64][65];
    int bx = blockIdx.x * 64;
    int by = blockIdx.y * 64;
    int tx = threadIdx.x & 63;
    int ty = threadIdx.x >> 6;
#pragma unroll
    for (int r = ty; r < 64; r += 4)
        tile[r][tx] = (f16)src[(size_t)(by + r) * HB + bx + tx];
    __syncthreads();
#pragma unroll
    for (int r = ty; r < 64; r += 4)
        dst[(size_t)(bx + r) * HB + by + tx] = tile[tx][r];
}

// ---------- convert/gather x [b][t][d] fp32 -> a16 [t*64+b][d] fp16 ----------
__global__ __launch_bounds__(256) void k_cvt_x(const float* __restrict__ x,
                                               f16* __restrict__ a16) {
    int r = blockIdx.x;  // r = t*64+b
    int d = threadIdx.x * 8;
    const float* src = x + ((size_t)(r & 63) * TT + (r >> 6)) * DD + d;
    float4 v0 = *(const float4*)src;
    float4 v1 = *(const float4*)(src + 4);
    f16x8 o = {(f16)v0.x, (f16)v0.y, (f16)v0.z, (f16)v0.w,
               (f16)v1.x, (f16)v1.y, (f16)v1.z, (f16)v1.w};
    *(f16x8*)(a16 + (size_t)r * DD + d) = o;
}

// ---------- phase 1: 128x128x32 LDS-staged MFMA GEMM, xw16 = a16 @ W + b ----------
__global__ __launch_bounds__(256) void k_gemm_xw_lds(const f16* __restrict__ a16,
                                                     const f16* __restrict__ W16T,
                                                     const float* __restrict__ bias,
                                                     f16* __restrict__ xw16) {
    __shared__ f16 As[128 * 32];
    __shared__ f16 Bs[128 * 32];
    int tid = threadIdx.x;
    int lane = tid & 63, w = tid >> 6;
    int wr = w >> 1, wc = w & 1;
    int lr = lane & 15, kg = lane >> 4;
    int rowBase = blockIdx.y * 128;
    int colBase = blockIdx.x * 128;

    f32x4 acc[4][4] = {};

    int r0 = tid >> 2, c0 = ((tid & 3) ^ ((r0 >> 1) & 3)) * 8;
    int u1 = tid + 256;
    int r1 = u1 >> 2, c1 = ((u1 & 3) ^ ((r1 >> 1) & 3)) * 8;
    const f16* gA0 = a16 + (size_t)(rowBase + r0) * DD + c0;
    const f16* gA1 = a16 + (size_t)(rowBase + r1) * DD + c1;
    const f16* gB0 = W16T + (size_t)(colBase + r0) * DD + c0;
    const f16* gB1 = W16T + (size_t)(colBase + r1) * DD + c1;
    f16* lA0 = As + (size_t)(w * 64) * 8;
    f16* lA1 = As + (size_t)(256 + w * 64) * 8;
    f16* lB0 = Bs + (size_t)(w * 64) * 8;
    f16* lB1 = Bs + (size_t)(256 + w * 64) * 8;

    for (int kk = 0; kk < DD; kk += 32) {
        gl_lds16(gA0 + kk, lA0);
        gl_lds16(gA1 + kk, lA1);
        gl_lds16(gB0 + kk, lB0);
        gl_lds16(gB1 + kk, lB1);
        __syncthreads();

        f16x8 af[4], bf[4];
#pragma unroll
        for (int mi = 0; mi < 4; ++mi) {
            int row = wr * 64 + mi * 16 + lr;
            af[mi] = *(const f16x8*)(As + row * 32 + (kg ^ ((row >> 1) & 3)) * 8);
        }
#pragma unroll
        for (int ni = 0; ni < 4; ++ni) {
            int rowb = wc * 64 + ni * 16 + lr;
            bf[ni] = *(const f16x8*)(Bs + rowb * 32 + (kg ^ ((rowb >> 1) & 3)) * 8);
        }
#pragma unroll
        for (int mi = 0; mi < 4; ++mi)
#pragma unroll
            for (int ni = 0; ni < 4; ++ni)
                acc[mi][ni] = __builtin_amdgcn_mfma_f32_16x16x32_f16(af[mi], bf[ni],
                                                                     acc[mi][ni], 0, 0, 0);
        __syncthreads();
    }

#pragma unroll
    for (int mi = 0; mi < 4; ++mi)
#pragma unroll
        for (int ni = 0; ni < 4; ++ni) {
            int col = colBase + wc * 64 + ni * 16 + lr;
            float bv = bias[col];
#pragma unroll
            for (int j = 0; j < 4; ++j) {
                int row = rowBase + wr * 64 + mi * 16 + kg * 4 + j;
                xw16[(size_t)row * HB + col] = (f16)(acc[mi][ni][j] + bv);
            }
        }
}

// ---------- phase 1 (fallback, small ws) ----------
__global__ __launch_bounds__(256) void k_gemm_xw_direct(const float* __restrict__ x,
                                                        const f16* __restrict__ W16T,
                                                        const float* __restrict__ bias,
                                                        f16* __restrict__ xw16) {
    int lane = threadIdx.x & 63;
    int w = threadIdx.x >> 6;
    int wr = w >> 1, wc = w & 1;
    int rowBase = blockIdx.y * 64 + wr * 32;
    int colBase = blockIdx.x * 64 + wc * 32;
    int lr = lane & 15;
    int kg = lane >> 4;

    f32x4 acc[2][2] = {};

    int r0 = rowBase + lr;
    int r1 = rowBase + 16 + lr;
    const float* xrow0 = x + ((size_t)(r0 & 63) * TT + (r0 >> 6)) * DD;
    const float* xrow1 = x + ((size_t)(r1 & 63) * TT + (r1 >> 6)) * DD;
    const f16* wrow0 = W16T + (size_t)(colBase + lr) * DD;
    const f16* wrow1 = W16T + (size_t)(colBase + 16 + lr) * DD;

    for (int kk = 0; kk < DD; kk += 32) {
        int k = kk + kg * 8;
        const float4* pa0 = reinterpret_cast<const float4*>(xrow0 + k);
        const float4* pa1 = reinterpret_cast<const float4*>(xrow1 + k);
        float4 a0l = pa0[0], a0h = pa0[1];
        float4 a1l = pa1[0], a1h = pa1[1];
        f16x8 a0 = {(f16)a0l.x, (f16)a0l.y, (f16)a0l.z, (f16)a0l.w,
                    (f16)a0h.x, (f16)a0h.y, (f16)a0h.z, (f16)a0h.w};
        f16x8 a1 = {(f16)a1l.x, (f16)a1l.y, (f16)a1l.z, (f16)a1l.w,
                    (f16)a1h.x, (f16)a1h.y, (f16)a1h.z, (f16)a1h.w};
        f16x8 b0 = *reinterpret_cast<const f16x8*>(wrow0 + k);
        f16x8 b1 = *reinterpret_cast<const f16x8*>(wrow1 + k);
        acc[0][0] = __builtin_amdgcn_mfma_f32_16x16x32_f16(a0, b0, acc[0][0], 0, 0, 0);
        acc[0][1] = __builtin_amdgcn_mfma_f32_16x16x32_f16(a0, b1, acc[0][1], 0, 0, 0);
        acc[1][0] = __builtin_amdgcn_mfma_f32_16x16x32_f16(a1, b0, acc[1][0], 0, 0, 0);
        acc[1][1] = __builtin_amdgcn_mfma_f32_16x16x32_f16(a1, b1, acc[1][1], 0, 0, 0);
    }

#pragma unroll
    for (int mi = 0; mi < 2; ++mi)
#pragma unroll
        for (int ni = 0; ni < 2; ++ni) {
            int col = colBase + ni * 16 + lr;
            float bv = bias[col];
#pragma unroll
            for (int j = 0; j < 4; ++j) {
                int row = rowBase + mi * 16 + kg * 4 + j;
                xw16[(size_t)row * HB + col] = (f16)(acc[mi][ni][j] + bv);
            }
        }
}

// ---------- phase 2: persistent recurrence, 64 WGs x 512 thr ----------
// WG owns 32 cols; wave w owns K slice [w*256,(w+1)*256); Wh frags in registers.
// NO fences, NO L2 invalidates in the loop:
//  - h stores: sc1 write-through (relaxed agent atomic) + per-wave vmcnt drain
//  - h loads: sc1 L3-coherent (relaxed agent atomic) — always fresh, no inv needed
//  - per-wave fine-grained wait: wave w needs only producers w*8..w*8+7 (8 flags,
//    8 readers each — no poll hot-spot), starts its loads+MFMA immediately
//  - h ring of 4 buffers (NB=4) makes buffer reuse safe under relaxed scheduling
__global__ __launch_bounds__(512) void k_rnn_persist(const f16* __restrict__ Wh16T,
                                                     const f16* __restrict__ xw16,
                                                     f16* __restrict__ hring,
                                                     float* __restrict__ dout,
                                                     u32* __restrict__ bar) {
    __shared__ float red[64][260];
    int tid = threadIdx.x;
    int lane = tid & 63, w = tid >> 6;
    int lr = lane & 15, kg = lane >> 4;
    int n0 = blockIdx.x * 32;

    // preload B fragments: Wh16T[n0+ni*16+lr][w*256 + s*32 + kg*8 .. +8]
    f16x8 bfrag[2][8];
#pragma unroll
    for (int ni = 0; ni < 2; ++ni) {
        const f16* brow = Wh16T + (size_t)(n0 + ni * 16 + lr) * HB + w * 256 + kg * 8;
#pragma unroll
        for (int s = 0; s < 8; ++s) bfrag[ni][s] = *(const f16x8*)(brow + s * 32);
    }

    int r_o = tid >> 3;      // 0..63
    int c4 = (tid & 7) * 4;  // 0,4,...,28
    int colbase = n0 + c4;
    int myflag = w * 8 + (lane & 7);  // producer WG this lane polls

    for (int t = 0; t < TT; ++t) {
        // xw load early (plain cached; written pre-dispatch — coherent at launch)
        u64 xwv = *(const u64*)(xw16 + ((size_t)t * BB + r_o) * HB + colbase);

        f32x4 acc[4][2] = {};
        if (t > 0) {
            // fine-grained wait: my wave's 8 K-slice producers flagged >= t
            u32 tgt = (u32)t;
            u32 v = __hip_atomic_load(bar + (size_t)myflag * 16, __ATOMIC_RELAXED,
                                      __HIP_MEMORY_SCOPE_AGENT);
            while (!__all(v >= tgt)) {
                __builtin_amdgcn_s_sleep(8);
                v = __hip_atomic_load(bar + (size_t)myflag * 16, __ATOMIC_RELAXED,
                                      __HIP_MEMORY_SCOPE_AGENT);
            }
            const f16* rbuf = hring + (size_t)(t & 3) * BB * HB;
            const f16* abase = rbuf + w * 256 + kg * 8;
#pragma unroll
            for (int m = 0; m < 4; ++m) {
                const f16* ar = abase + (size_t)(m * 16 + lr) * HB;
                u64 q0[8], q1[8];
#pragma unroll
                for (int s = 0; s < 8; ++s) {
                    q0[s] = __hip_atomic_load((const u64*)(ar + s * 32), __ATOMIC_RELAXED,
                                              __HIP_MEMORY_SCOPE_AGENT);
                    q1[s] = __hip_atomic_load((const u64*)(ar + s * 32 + 4), __ATOMIC_RELAXED,
                                              __HIP_MEMORY_SCOPE_AGENT);
                }
#pragma unroll
                for (int s = 0; s < 8; ++s) {
                    union { u64 q[2]; f16x8 v8; } a;
                    a.q[0] = q0[s];
                    a.q[1] = q1[s];
                    acc[m][0] = __builtin_amdgcn_mfma_f32_16x16x32_f16(a.v8, bfrag[0][s],
                                                                       acc[m][0], 0, 0, 0);
                    acc[m][1] = __builtin_amdgcn_mfma_f32_16x16x32_f16(a.v8, bfrag[1][s],
                                                                       acc[m][1], 0, 0, 0);
                }
            }
        }

        // partials -> LDS: red[row][w*32 + ni*16 + lr]
#pragma unroll
        for (int m = 0; m < 4; ++m)
#pragma unroll
            for (int ni = 0; ni < 2; ++ni) {
                int rbase = m * 16 + kg * 4;
#pragma unroll
                for (int j = 0; j < 4; ++j)
                    red[rbase + j][w * 32 + ni * 16 + lr] = acc[m][ni][j];
            }
        __syncthreads();  // (A)

        // cross-wave reduce
        float4 sum = {0.f, 0.f, 0.f, 0.f};
#pragma unroll
        for (int ww = 0; ww < 8; ++ww) {
            float4 v = *(const float4*)&red[r_o][ww * 32 + c4];
            sum.x += v.x; sum.y += v.y; sum.z += v.z; sum.w += v.w;
        }
        union { u64 q; f16 h[4]; } xwu;
        xwu.q = xwv;
        float h0v = tanhf(sum.x + (float)xwu.h[0]);
        float h1v = tanhf(sum.y + (float)xwu.h[1]);
        float h2v = tanhf(sum.z + (float)xwu.h[2]);
        float h3v = tanhf(sum.w + (float)xwu.h[3]);

        if (t == TT - 1) {
            float4 o = {h0v, h1v, h2v, h3v};
            *(float4*)(dout + (size_t)r_o * HB + colbase) = o;
        } else {
            union { u64 q; f16 h[4]; } ho;
            ho.h[0] = (f16)h0v; ho.h[1] = (f16)h1v;
            ho.h[2] = (f16)h2v; ho.h[3] = (f16)h3v;
            f16* wbuf = hring + (size_t)((t + 1) & 3) * BB * HB;
            __hip_atomic_store((u64*)(wbuf + (size_t)r_o * HB + colbase), ho.q,
                               __ATOMIC_RELAXED, __HIP_MEMORY_SCOPE_AGENT);
            asm volatile("s_waitcnt vmcnt(0)" ::: "memory");  // my h at L3
            __syncthreads();  // (B): all waves drained + LDS reuse protected
            if (tid == 0)
                __hip_atomic_store(bar + (size_t)blockIdx.x * 16, (u32)(t + 1),
                                   __ATOMIC_RELAXED, __HIP_MEMORY_SCOPE_AGENT);
        }
    }
}

extern "C" void kernel_launch(void* const* d_in, const int* in_sizes, int n_in,
                              void* d_out, int out_size, void* d_ws, size_t ws_size,
                              hipStream_t stream) {
    const float* x = (const float*)d_in[0];
    const float* W = (const float*)d_in[1];
    const float* Wh = (const float*)d_in[2];
    const float* bias = (const float*)d_in[3];
    float* dout = (float*)d_out;

    char* ws = (char*)d_ws;
    const size_t SZ_WT = (size_t)HB * DD * 2;         // 8 MB
    const size_t SZ_RING = (size_t)4 * BB * HB * 2;   // 1 MB
    const size_t SZ_XW = (size_t)TT * BB * HB * 2;    // 64 MB
    const size_t OFF_W = 0;
    const size_t OFF_WH = OFF_W + SZ_WT;
    const size_t OFF_RING = OFF_WH + SZ_WT;
    const size_t OFF_BAR = OFF_RING + SZ_RING;
    const size_t OFF_XW = OFF_BAR + 8192;
    const size_t OFF_X16 = OFF_XW + SZ_XW;
    const size_t NEED_FULL = OFF_X16 + (size_t)TT * BB * DD * 2;

    f16* W16T = (f16*)(ws + OFF_W);
    f16* Wh16T = (f16*)(ws + OFF_WH);
    f16* hring = (f16*)(ws + OFF_RING);
    u32* bar = (u32*)(ws + OFF_BAR);
    f16* xw16 = (f16*)(ws + OFF_XW);
    f16* x16 = (f16*)(ws + OFF_X16);

    dim3 tgrid(32, 32);
    k_transpose_cvt<<<tgrid, 256, 0, stream>>>(W, W16T);
    k_transpose_cvt<<<tgrid, 256, 0, stream>>>(Wh, Wh16T);

    if (ws_size >= NEED_FULL) {
        k_cvt_x<<<TT * BB, 256, 0, stream>>>(x, x16);
        k_gemm_xw_lds<<<dim3(HB / 128, TT * BB / 128), 256, 0, stream>>>(x16, W16T, bias, xw16);
    } else {
        k_gemm_xw_direct<<<dim3(HB / 64, TT * BB / 64), 256, 0, stream>>>(x, W16T, bias, xw16);
    }

    hipMemsetAsync(bar, 0, 8192, stream);
    k_rnn_persist<<<CWG, 512, 0, stream>>>(Wh16T, xw16, hring, dout, bar);
}

// Round 7
// 3177.855 us; speedup vs baseline: 1.3819x; 1.3819x over previous
//
#include <hip/hip_runtime.h>
#include <hip/hip_bf16.h>
#include <hip/hip_fp16.h>

typedef _Float16 f16;
typedef _Float16 f16x8 __attribute__((ext_vector_type(8)));
typedef float f32x4 __attribute__((ext_vector_type(4)));
typedef unsigned int u32;
typedef unsigned long long u64;

#define HB 2048
#define DD 2048
#define TT 256
#define BB 64
#define CWG 64  // persistent WGs (32 cols each)

typedef const __attribute__((address_space(1))) u32 gu32;
typedef __attribute__((address_space(3))) u32 lu32;

__device__ __forceinline__ void gl_lds16(const void* g, void* l) {
    __builtin_amdgcn_global_load_lds((gu32*)g, (lu32*)l, 16, 0, 0);
}

// 8x global_load_dwordx4 sc1 (L2-bypass, read at coherence point = L3)
#define LOADM(dst, ar)                                                        \
    asm volatile("global_load_dwordx4 %0, %8, off sc1\n\t"                    \
                 "global_load_dwordx4 %1, %8, off offset:64 sc1\n\t"          \
                 "global_load_dwordx4 %2, %8, off offset:128 sc1\n\t"         \
                 "global_load_dwordx4 %3, %8, off offset:192 sc1\n\t"         \
                 "global_load_dwordx4 %4, %8, off offset:256 sc1\n\t"         \
                 "global_load_dwordx4 %5, %8, off offset:320 sc1\n\t"         \
                 "global_load_dwordx4 %6, %8, off offset:384 sc1\n\t"         \
                 "global_load_dwordx4 %7, %8, off offset:448 sc1"             \
                 : "=&v"(dst[0]), "=&v"(dst[1]), "=&v"(dst[2]), "=&v"(dst[3]),\
                   "=&v"(dst[4]), "=&v"(dst[5]), "=&v"(dst[6]), "=&v"(dst[7]) \
                 : "v"(ar)                                                    \
                 : "memory")

// ---------- transpose + convert fp32 [R][C] -> fp16 [C][R] (square 2048) ----------
__global__ __launch_bounds__(256) void k_transpose_cvt(const float* __restrict__ src,
                                                       f16* __restrict__ dst) {
    __shared__ f16 tile[64][65];
    int bx = blockIdx.x * 64;
    int by = blockIdx.y * 64;
    int tx = threadIdx.x & 63;
    int ty = threadIdx.x >> 6;
#pragma unroll
    for (int r = ty; r < 64; r += 4)
        tile[r][tx] = (f16)src[(size_t)(by + r) * HB + bx + tx];
    __syncthreads();
#pragma unroll
    for (int r = ty; r < 64; r += 4)
        dst[(size_t)(bx + r) * HB + by + tx] = tile[tx][r];
}

// ---------- convert/gather x [b][t][d] fp32 -> a16 [t*64+b][d] fp16 ----------
__global__ __launch_bounds__(256) void k_cvt_x(const float* __restrict__ x,
                                               f16* __restrict__ a16) {
    int r = blockIdx.x;  // r = t*64+b
    int d = threadIdx.x * 8;
    const float* src = x + ((size_t)(r & 63) * TT + (r >> 6)) * DD + d;
    float4 v0 = *(const float4*)src;
    float4 v1 = *(const float4*)(src + 4);
    f16x8 o = {(f16)v0.x, (f16)v0.y, (f16)v0.z, (f16)v0.w,
               (f16)v1.x, (f16)v1.y, (f16)v1.z, (f16)v1.w};
    *(f16x8*)(a16 + (size_t)r * DD + d) = o;
}

// ---------- phase 1: 128x128x32 LDS-staged MFMA GEMM, xw16 = a16 @ W + b ----------
__global__ __launch_bounds__(256) void k_gemm_xw_lds(const f16* __restrict__ a16,
                                                     const f16* __restrict__ W16T,
                                                     const float* __restrict__ bias,
                                                     f16* __restrict__ xw16) {
    __shared__ f16 As[128 * 32];
    __shared__ f16 Bs[128 * 32];
    int tid = threadIdx.x;
    int lane = tid & 63, w = tid >> 6;
    int wr = w >> 1, wc = w & 1;
    int lr = lane & 15, kg = lane >> 4;
    int rowBase = blockIdx.y * 128;
    int colBase = blockIdx.x * 128;

    f32x4 acc[4][4] = {};

    int r0 = tid >> 2, c0 = ((tid & 3) ^ ((r0 >> 1) & 3)) * 8;
    int u1 = tid + 256;
    int r1 = u1 >> 2, c1 = ((u1 & 3) ^ ((r1 >> 1) & 3)) * 8;
    const f16* gA0 = a16 + (size_t)(rowBase + r0) * DD + c0;
    const f16* gA1 = a16 + (size_t)(rowBase + r1) * DD + c1;
    const f16* gB0 = W16T + (size_t)(colBase + r0) * DD + c0;
    const f16* gB1 = W16T + (size_t)(colBase + r1) * DD + c1;
    f16* lA0 = As + (size_t)(w * 64) * 8;
    f16* lA1 = As + (size_t)(256 + w * 64) * 8;
    f16* lB0 = Bs + (size_t)(w * 64) * 8;
    f16* lB1 = Bs + (size_t)(256 + w * 64) * 8;

    for (int kk = 0; kk < DD; kk += 32) {
        gl_lds16(gA0 + kk, lA0);
        gl_lds16(gA1 + kk, lA1);
        gl_lds16(gB0 + kk, lB0);
        gl_lds16(gB1 + kk, lB1);
        __syncthreads();

        f16x8 af[4], bf[4];
#pragma unroll
        for (int mi = 0; mi < 4; ++mi) {
            int row = wr * 64 + mi * 16 + lr;
            af[mi] = *(const f16x8*)(As + row * 32 + (kg ^ ((row >> 1) & 3)) * 8);
        }
#pragma unroll
        for (int ni = 0; ni < 4; ++ni) {
            int rowb = wc * 64 + ni * 16 + lr;
            bf[ni] = *(const f16x8*)(Bs + rowb * 32 + (kg ^ ((rowb >> 1) & 3)) * 8);
        }
#pragma unroll
        for (int mi = 0; mi < 4; ++mi)
#pragma unroll
            for (int ni = 0; ni < 4; ++ni)
                acc[mi][ni] = __builtin_amdgcn_mfma_f32_16x16x32_f16(af[mi], bf[ni],
                                                                     acc[mi][ni], 0, 0, 0);
        __syncthreads();
    }

#pragma unroll
    for (int mi = 0; mi < 4; ++mi)
#pragma unroll
        for (int ni = 0; ni < 4; ++ni) {
            int col = colBase + wc * 64 + ni * 16 + lr;
            float bv = bias[col];
#pragma unroll
            for (int j = 0; j < 4; ++j) {
                int row = rowBase + wr * 64 + mi * 16 + kg * 4 + j;
                xw16[(size_t)row * HB + col] = (f16)(acc[mi][ni][j] + bv);
            }
        }
}

// ---------- phase 1 (fallback, small ws) ----------
__global__ __launch_bounds__(256) void k_gemm_xw_direct(const float* __restrict__ x,
                                                        const f16* __restrict__ W16T,
                                                        const float* __restrict__ bias,
                                                        f16* __restrict__ xw16) {
    int lane = threadIdx.x & 63;
    int w = threadIdx.x >> 6;
    int wr = w >> 1, wc = w & 1;
    int rowBase = blockIdx.y * 64 + wr * 32;
    int colBase = blockIdx.x * 64 + wc * 32;
    int lr = lane & 15;
    int kg = lane >> 4;

    f32x4 acc[2][2] = {};

    int r0 = rowBase + lr;
    int r1 = rowBase + 16 + lr;
    const float* xrow0 = x + ((size_t)(r0 & 63) * TT + (r0 >> 6)) * DD;
    const float* xrow1 = x + ((size_t)(r1 & 63) * TT + (r1 >> 6)) * DD;
    const f16* wrow0 = W16T + (size_t)(colBase + lr) * DD;
    const f16* wrow1 = W16T + (size_t)(colBase + 16 + lr) * DD;

    for (int kk = 0; kk < DD; kk += 32) {
        int k = kk + kg * 8;
        const float4* pa0 = reinterpret_cast<const float4*>(xrow0 + k);
        const float4* pa1 = reinterpret_cast<const float4*>(xrow1 + k);
        float4 a0l = pa0[0], a0h = pa0[1];
        float4 a1l = pa1[0], a1h = pa1[1];
        f16x8 a0 = {(f16)a0l.x, (f16)a0l.y, (f16)a0l.z, (f16)a0l.w,
                    (f16)a0h.x, (f16)a0h.y, (f16)a0h.z, (f16)a0h.w};
        f16x8 a1 = {(f16)a1l.x, (f16)a1l.y, (f16)a1l.z, (f16)a1l.w,
                    (f16)a1h.x, (f16)a1h.y, (f16)a1h.z, (f16)a1h.w};
        f16x8 b0 = *reinterpret_cast<const f16x8*>(wrow0 + k);
        f16x8 b1 = *reinterpret_cast<const f16x8*>(wrow1 + k);
        acc[0][0] = __builtin_amdgcn_mfma_f32_16x16x32_f16(a0, b0, acc[0][0], 0, 0, 0);
        acc[0][1] = __builtin_amdgcn_mfma_f32_16x16x32_f16(a0, b1, acc[0][1], 0, 0, 0);
        acc[1][0] = __builtin_amdgcn_mfma_f32_16x16x32_f16(a1, b0, acc[1][0], 0, 0, 0);
        acc[1][1] = __builtin_amdgcn_mfma_f32_16x16x32_f16(a1, b1, acc[1][1], 0, 0, 0);
    }

#pragma unroll
    for (int mi = 0; mi < 2; ++mi)
#pragma unroll
        for (int ni = 0; ni < 2; ++ni) {
            int col = colBase + ni * 16 + lr;
            float bv = bias[col];
#pragma unroll
            for (int j = 0; j < 4; ++j) {
                int row = rowBase + mi * 16 + kg * 4 + j;
                xw16[(size_t)row * HB + col] = (f16)(acc[mi][ni][j] + bv);
            }
        }
}

// ---------- phase 2: persistent recurrence, 64 WGs x 512 thr ----------
// h exchange lives in L3:
//  - producer: PLAIN cached h stores (dirty L2) -> fence(release, agent)
//    (= buffer_wbl2 sc1: flush L2->L3, allocating) -> flag store
//  - consumer: sc1 asm loads read the coherence point (L3) directly.
//    NO acquire fence, NO buffer_inv anywhere -> no inv/dirty races, no refill storms.
//  - 2-deep software pipeline on the 4 m-blocks with counted vmcnt waits.
__global__ __launch_bounds__(512) void k_rnn_persist(const f16* __restrict__ Wh16T,
                                                     const f16* __restrict__ xw16,
                                                     f16* __restrict__ hring,
                                                     float* __restrict__ dout,
                                                     u32* __restrict__ bar) {
    __shared__ float red[64][260];
    int tid = threadIdx.x;
    int lane = tid & 63, w = tid >> 6;
    int lr = lane & 15, kg = lane >> 4;
    int n0 = blockIdx.x * 32;

    // preload B fragments: Wh16T[n0+ni*16+lr][w*256 + s*32 + kg*8 .. +8]
    f16x8 bfrag[2][8];
#pragma unroll
    for (int ni = 0; ni < 2; ++ni) {
        const f16* brow = Wh16T + (size_t)(n0 + ni * 16 + lr) * HB + w * 256 + kg * 8;
#pragma unroll
        for (int s = 0; s < 8; ++s) bfrag[ni][s] = *(const f16x8*)(brow + s * 32);
    }

    int r_o = tid >> 3;      // 0..63
    int c4 = (tid & 7) * 4;  // 0,4,...,28
    int colbase = n0 + c4;

    for (int t = 0; t < TT; ++t) {
        // xw load early (plain cached, streamed from HBM once)
        u64 xwv = *(const u64*)(xw16 + ((size_t)t * BB + r_o) * HB + colbase);

        f32x4 acc[4][2] = {};
        if (t > 0) {
            // full barrier: every wave polls all 64 flags (lane -> flag)
            u32 tgt = (u32)t;
            u32 v = __hip_atomic_load(bar + (size_t)lane * 16, __ATOMIC_RELAXED,
                                      __HIP_MEMORY_SCOPE_AGENT);
            while (!__all(v >= tgt)) {
                __builtin_amdgcn_s_sleep(2);
                v = __hip_atomic_load(bar + (size_t)lane * 16, __ATOMIC_RELAXED,
                                      __HIP_MEMORY_SCOPE_AGENT);
            }

            const f16* rbuf = hring + (size_t)(t & 3) * BB * HB;
            const f16* abase = rbuf + w * 256 + kg * 8;
            f16x8 hva[8], hvb[8];
            LOADM(hva, abase + (size_t)(0 * 16 + lr) * HB);
            LOADM(hvb, abase + (size_t)(1 * 16 + lr) * HB);

            // m=0 (hva)
            asm volatile("s_waitcnt vmcnt(8)" ::: "memory");
            __builtin_amdgcn_sched_barrier(0);
#pragma unroll
            for (int s = 0; s < 8; ++s) {
                acc[0][0] = __builtin_amdgcn_mfma_f32_16x16x32_f16(hva[s], bfrag[0][s],
                                                                   acc[0][0], 0, 0, 0);
                acc[0][1] = __builtin_amdgcn_mfma_f32_16x16x32_f16(hva[s], bfrag[1][s],
                                                                   acc[0][1], 0, 0, 0);
            }
            LOADM(hva, abase + (size_t)(2 * 16 + lr) * HB);

            // m=1 (hvb)
            asm volatile("s_waitcnt vmcnt(8)" ::: "memory");
            __builtin_amdgcn_sched_barrier(0);
#pragma unroll
            for (int s = 0; s < 8; ++s) {
                acc[1][0] = __builtin_amdgcn_mfma_f32_16x16x32_f16(hvb[s], bfrag[0][s],
                                                                   acc[1][0], 0, 0, 0);
                acc[1][1] = __builtin_amdgcn_mfma_f32_16x16x32_f16(hvb[s], bfrag[1][s],
                                                                   acc[1][1], 0, 0, 0);
            }
            LOADM(hvb, abase + (size_t)(3 * 16 + lr) * HB);

            // m=2 (hva)
            asm volatile("s_waitcnt vmcnt(8)" ::: "memory");
            __builtin_amdgcn_sched_barrier(0);
#pragma unroll
            for (int s = 0; s < 8; ++s) {
                acc[2][0] = __builtin_amdgcn_mfma_f32_16x16x32_f16(hva[s], bfrag[0][s],
                                                                   acc[2][0], 0, 0, 0);
                acc[2][1] = __builtin_amdgcn_mfma_f32_16x16x32_f16(hva[s], bfrag[1][s],
                                                                   acc[2][1], 0, 0, 0);
            }

            // m=3 (hvb)
            asm volatile("s_waitcnt vmcnt(0)" ::: "memory");
            __builtin_amdgcn_sched_barrier(0);
#pragma unroll
            for (int s = 0; s < 8; ++s) {
                acc[3][0] = __builtin_amdgcn_mfma_f32_16x16x32_f16(hvb[s], bfrag[0][s],
                                                                   acc[3][0], 0, 0, 0);
                acc[3][1] = __builtin_amdgcn_mfma_f32_16x16x32_f16(hvb[s], bfrag[1][s],
                                                                   acc[3][1], 0, 0, 0);
            }
        }

        // partials -> LDS: red[row][w*32 + ni*16 + lr]
#pragma unroll
        for (int m = 0; m < 4; ++m)
#pragma unroll
            for (int ni = 0; ni < 2; ++ni) {
                int rbase = m * 16 + kg * 4;
#pragma unroll
                for (int j = 0; j < 4; ++j)
                    red[rbase + j][w * 32 + ni * 16 + lr] = acc[m][ni][j];
            }
        __syncthreads();  // (A)

        // cross-wave reduce
        float4 sum = {0.f, 0.f, 0.f, 0.f};
#pragma unroll
        for (int ww = 0; ww < 8; ++ww) {
            float4 v = *(const float4*)&red[r_o][ww * 32 + c4];
            sum.x += v.x; sum.y += v.y; sum.z += v.z; sum.w += v.w;
        }
        union { u64 q; f16 h[4]; } xwu;
        xwu.q = xwv;
        float h0v = tanhf(sum.x + (float)xwu.h[0]);
        float h1v = tanhf(sum.y + (float)xwu.h[1]);
        float h2v = tanhf(sum.z + (float)xwu.h[2]);
        float h3v = tanhf(sum.w + (float)xwu.h[3]);

        if (t == TT - 1) {
            float4 o = {h0v, h1v, h2v, h3v};
            *(float4*)(dout + (size_t)r_o * HB + colbase) = o;
        } else {
            union { u64 q; f16 h[4]; } ho;
            ho.h[0] = (f16)h0v; ho.h[1] = (f16)h1v;
            ho.h[2] = (f16)h2v; ho.h[3] = (f16)h3v;
            f16* wbuf = hring + (size_t)((t + 1) & 3) * BB * HB;
            *(u64*)(wbuf + (size_t)r_o * HB + colbase) = ho.q;  // plain cached store
            asm volatile("s_waitcnt vmcnt(0)" ::: "memory");    // landed in L2 (L1 is WT)
            __syncthreads();  // (B): all waves' stores in L2; LDS reuse protected
            if (tid == 0) {
                // flush dirty L2 -> L3 (buffer_wbl2 sc1), then raise flag
                __builtin_amdgcn_fence(__ATOMIC_RELEASE, "agent");
                __hip_atomic_store(bar + (size_t)blockIdx.x * 16, (u32)(t + 1),
                                   __ATOMIC_RELAXED, __HIP_MEMORY_SCOPE_AGENT);
            }
        }
    }
}

extern "C" void kernel_launch(void* const* d_in, const int* in_sizes, int n_in,
                              void* d_out, int out_size, void* d_ws, size_t ws_size,
                              hipStream_t stream) {
    const float* x = (const float*)d_in[0];
    const float* W = (const float*)d_in[1];
    const float* Wh = (const float*)d_in[2];
    const float* bias = (const float*)d_in[3];
    float* dout = (float*)d_out;

    char* ws = (char*)d_ws;
    const size_t SZ_WT = (size_t)HB * DD * 2;        // 8 MB
    const size_t SZ_RING = (size_t)4 * BB * HB * 2;  // 1 MB
    const size_t SZ_XW = (size_t)TT * BB * HB * 2;   // 64 MB
    const size_t OFF_W = 0;
    const size_t OFF_WH = OFF_W + SZ_WT;
    const size_t OFF_RING = OFF_WH + SZ_WT;
    const size_t OFF_BAR = OFF_RING + SZ_RING;
    const size_t OFF_XW = OFF_BAR + 8192;
    const size_t OFF_X16 = OFF_XW + SZ_XW;
    const size_t NEED_FULL = OFF_X16 + (size_t)TT * BB * DD * 2;

    f16* W16T = (f16*)(ws + OFF_W);
    f16* Wh16T = (f16*)(ws + OFF_WH);
    f16* hring = (f16*)(ws + OFF_RING);
    u32* bar = (u32*)(ws + OFF_BAR);
    f16* xw16 = (f16*)(ws + OFF_XW);
    f16* x16 = (f16*)(ws + OFF_X16);

    dim3 tgrid(32, 32);
    k_transpose_cvt<<<tgrid, 256, 0, stream>>>(W, W16T);
    k_transpose_cvt<<<tgrid, 256, 0, stream>>>(Wh, Wh16T);

    if (ws_size >= NEED_FULL) {
        k_cvt_x<<<TT * BB, 256, 0, stream>>>(x, x16);
        k_gemm_xw_lds<<<dim3(HB / 128, TT * BB / 128), 256, 0, stream>>>(x16, W16T, bias, xw16);
    } else {
        k_gemm_xw_direct<<<dim3(HB / 64, TT * BB / 64), 256, 0, stream>>>(x, W16T, bias, xw16);
    }

    hipMemsetAsync(bar, 0, 8192, stream);
    k_rnn_persist<<<CWG, 512, 0, stream>>>(Wh16T, xw16, hring, dout, bar);
}

// Round 8
// 2537.789 us; speedup vs baseline: 1.7304x; 1.2522x over previous
//
#include <hip/hip_runtime.h>
#include <hip/hip_bf16.h>
#include <hip/hip_fp16.h>

typedef _Float16 f16;
typedef _Float16 f16x8 __attribute__((ext_vector_type(8)));
typedef float f32x4 __attribute__((ext_vector_type(4)));
typedef unsigned int u32;
typedef unsigned long long u64;

#define HB 2048
#define DD 2048
#define TT 256
#define BB 64
#define CWG 64  // persistent WGs (32 cols each)

typedef const __attribute__((address_space(1))) u32 gu32;
typedef __attribute__((address_space(3))) u32 lu32;

__device__ __forceinline__ void gl_lds16(const void* g, void* l) {
    __builtin_amdgcn_global_load_lds((gu32*)g, (lu32*)l, 16, 0, 0);
}

// 8x global_load_dwordx4 sc1 (bypass L1/L2, read at coherence point)
#define LOADM(dst, ar)                                                        \
    asm volatile("global_load_dwordx4 %0, %8, off sc1\n\t"                    \
                 "global_load_dwordx4 %1, %8, off offset:64 sc1\n\t"          \
                 "global_load_dwordx4 %2, %8, off offset:128 sc1\n\t"         \
                 "global_load_dwordx4 %3, %8, off offset:192 sc1\n\t"         \
                 "global_load_dwordx4 %4, %8, off offset:256 sc1\n\t"         \
                 "global_load_dwordx4 %5, %8, off offset:320 sc1\n\t"         \
                 "global_load_dwordx4 %6, %8, off offset:384 sc1\n\t"         \
                 "global_load_dwordx4 %7, %8, off offset:448 sc1"             \
                 : "=&v"(dst[0]), "=&v"(dst[1]), "=&v"(dst[2]), "=&v"(dst[3]),\
                   "=&v"(dst[4]), "=&v"(dst[5]), "=&v"(dst[6]), "=&v"(dst[7]) \
                 : "v"(ar)                                                    \
                 : "memory")

#define VMCNT(n) asm volatile("s_waitcnt vmcnt(" #n ")" ::: "memory")

// any 8B chunk still equal to the 0xFF poison? (f16 0xFFFF = NaN, tanh never makes it)
__device__ __forceinline__ int chk8(const f16x8* v) {
    u64 bad = 0;
#pragma unroll
    for (int s = 0; s < 8; ++s) {
        union { f16x8 v8; u64 q[2]; } u;
        u.v8 = v[s];
        bad |= (u.q[0] == ~0ull) ? 1ull : 0ull;
        bad |= (u.q[1] == ~0ull) ? 1ull : 0ull;
    }
    return bad == 0;
}

// ---------- transpose + convert fp32 [R][C] -> fp16 [C][R] (square 2048) ----------
__global__ __launch_bounds__(256) void k_transpose_cvt(const float* __restrict__ src,
                                                       f16* __restrict__ dst) {
    __shared__ f16 tile[64][65];
    int bx = blockIdx.x * 64;
    int by = blockIdx.y * 64;
    int tx = threadIdx.x & 63;
    int ty = threadIdx.x >> 6;
#pragma unroll
    for (int r = ty; r < 64; r += 4)
        tile[r][tx] = (f16)src[(size_t)(by + r) * HB + bx + tx];
    __syncthreads();
#pragma unroll
    for (int r = ty; r < 64; r += 4)
        dst[(size_t)(bx + r) * HB + by + tx] = tile[tx][r];
}

// ---------- convert/gather x [b][t][d] fp32 -> a16 [t*64+b][d] fp16 ----------
__global__ __launch_bounds__(256) void k_cvt_x(const float* __restrict__ x,
                                               f16* __restrict__ a16) {
    int r = blockIdx.x;  // r = t*64+b
    int d = threadIdx.x * 8;
    const float* src = x + ((size_t)(r & 63) * TT + (r >> 6)) * DD + d;
    float4 v0 = *(const float4*)src;
    float4 v1 = *(const float4*)(src + 4);
    f16x8 o = {(f16)v0.x, (f16)v0.y, (f16)v0.z, (f16)v0.w,
               (f16)v1.x, (f16)v1.y, (f16)v1.z, (f16)v1.w};
    *(f16x8*)(a16 + (size_t)r * DD + d) = o;
}

// ---------- phase 1: 128x128x32 LDS-staged MFMA GEMM, xw16 = a16 @ W + b ----------
__global__ __launch_bounds__(256) void k_gemm_xw_lds(const f16* __restrict__ a16,
                                                     const f16* __restrict__ W16T,
                                                     const float* __restrict__ bias,
                                                     f16* __restrict__ xw16) {
    __shared__ f16 As[128 * 32];
    __shared__ f16 Bs[128 * 32];
    int tid = threadIdx.x;
    int lane = tid & 63, w = tid >> 6;
    int wr = w >> 1, wc = w & 1;
    int lr = lane & 15, kg = lane >> 4;
    int rowBase = blockIdx.y * 128;
    int colBase = blockIdx.x * 128;

    f32x4 acc[4][4] = {};

    int r0 = tid >> 2, c0 = ((tid & 3) ^ ((r0 >> 1) & 3)) * 8;
    int u1 = tid + 256;
    int r1 = u1 >> 2, c1 = ((u1 & 3) ^ ((r1 >> 1) & 3)) * 8;
    const f16* gA0 = a16 + (size_t)(rowBase + r0) * DD + c0;
    const f16* gA1 = a16 + (size_t)(rowBase + r1) * DD + c1;
    const f16* gB0 = W16T + (size_t)(colBase + r0) * DD + c0;
    const f16* gB1 = W16T + (size_t)(colBase + r1) * DD + c1;
    f16* lA0 = As + (size_t)(w * 64) * 8;
    f16* lA1 = As + (size_t)(256 + w * 64) * 8;
    f16* lB0 = Bs + (size_t)(w * 64) * 8;
    f16* lB1 = Bs + (size_t)(256 + w * 64) * 8;

    for (int kk = 0; kk < DD; kk += 32) {
        gl_lds16(gA0 + kk, lA0);
        gl_lds16(gA1 + kk, lA1);
        gl_lds16(gB0 + kk, lB0);
        gl_lds16(gB1 + kk, lB1);
        __syncthreads();

        f16x8 af[4], bf[4];
#pragma unroll
        for (int mi = 0; mi < 4; ++mi) {
            int row = wr * 64 + mi * 16 + lr;
            af[mi] = *(const f16x8*)(As + row * 32 + (kg ^ ((row >> 1) & 3)) * 8);
        }
#pragma unroll
        for (int ni = 0; ni < 4; ++ni) {
            int rowb = wc * 64 + ni * 16 + lr;
            bf[ni] = *(const f16x8*)(Bs + rowb * 32 + (kg ^ ((rowb >> 1) & 3)) * 8);
        }
#pragma unroll
        for (int mi = 0; mi < 4; ++mi)
#pragma unroll
            for (int ni = 0; ni < 4; ++ni)
                acc[mi][ni] = __builtin_amdgcn_mfma_f32_16x16x32_f16(af[mi], bf[ni],
                                                                     acc[mi][ni], 0, 0, 0);
        __syncthreads();
    }

#pragma unroll
    for (int mi = 0; mi < 4; ++mi)
#pragma unroll
        for (int ni = 0; ni < 4; ++ni) {
            int col = colBase + wc * 64 + ni * 16 + lr;
            float bv = bias[col];
#pragma unroll
            for (int j = 0; j < 4; ++j) {
                int row = rowBase + wr * 64 + mi * 16 + kg * 4 + j;
                xw16[(size_t)row * HB + col] = (f16)(acc[mi][ni][j] + bv);
            }
        }
}

// ---------- fallback (small ws): direct GEMM + per-step kernels ----------
__global__ __launch_bounds__(256) void k_gemm_xw_direct(const float* __restrict__ x,
                                                        const f16* __restrict__ W16T,
                                                        const float* __restrict__ bias,
                                                        f16* __restrict__ xw16) {
    int lane = threadIdx.x & 63;
    int w = threadIdx.x >> 6;
    int wr = w >> 1, wc = w & 1;
    int rowBase = blockIdx.y * 64 + wr * 32;
    int colBase = blockIdx.x * 64 + wc * 32;
    int lr = lane & 15;
    int kg = lane >> 4;

    f32x4 acc[2][2] = {};

    int r0 = rowBase + lr;
    int r1 = rowBase + 16 + lr;
    const float* xrow0 = x + ((size_t)(r0 & 63) * TT + (r0 >> 6)) * DD;
    const float* xrow1 = x + ((size_t)(r1 & 63) * TT + (r1 >> 6)) * DD;
    const f16* wrow0 = W16T + (size_t)(colBase + lr) * DD;
    const f16* wrow1 = W16T + (size_t)(colBase + 16 + lr) * DD;

    for (int kk = 0; kk < DD; kk += 32) {
        int k = kk + kg * 8;
        const float4* pa0 = reinterpret_cast<const float4*>(xrow0 + k);
        const float4* pa1 = reinterpret_cast<const float4*>(xrow1 + k);
        float4 a0l = pa0[0], a0h = pa0[1];
        float4 a1l = pa1[0], a1h = pa1[1];
        f16x8 a0 = {(f16)a0l.x, (f16)a0l.y, (f16)a0l.z, (f16)a0l.w,
                    (f16)a0h.x, (f16)a0h.y, (f16)a0h.z, (f16)a0h.w};
        f16x8 a1 = {(f16)a1l.x, (f16)a1l.y, (f16)a1l.z, (f16)a1l.w,
                    (f16)a1h.x, (f16)a1h.y, (f16)a1h.z, (f16)a1h.w};
        f16x8 b0 = *reinterpret_cast<const f16x8*>(wrow0 + k);
        f16x8 b1 = *reinterpret_cast<const f16x8*>(wrow1 + k);
        acc[0][0] = __builtin_amdgcn_mfma_f32_16x16x32_f16(a0, b0, acc[0][0], 0, 0, 0);
        acc[0][1] = __builtin_amdgcn_mfma_f32_16x16x32_f16(a0, b1, acc[0][1], 0, 0, 0);
        acc[1][0] = __builtin_amdgcn_mfma_f32_16x16x32_f16(a1, b0, acc[1][0], 0, 0, 0);
        acc[1][1] = __builtin_amdgcn_mfma_f32_16x16x32_f16(a1, b1, acc[1][1], 0, 0, 0);
    }

#pragma unroll
    for (int mi = 0; mi < 2; ++mi)
#pragma unroll
        for (int ni = 0; ni < 2; ++ni) {
            int col = colBase + ni * 16 + lr;
            float bv = bias[col];
#pragma unroll
            for (int j = 0; j < 4; ++j) {
                int row = rowBase + mi * 16 + kg * 4 + j;
                xw16[(size_t)row * HB + col] = (f16)(acc[mi][ni][j] + bv);
            }
        }
}

__global__ __launch_bounds__(128) void k_rnn_step(const f16* __restrict__ hin,
                                                  const f16* __restrict__ WhT,
                                                  const f16* __restrict__ xw_t,
                                                  f16* __restrict__ hout,
                                                  float* __restrict__ dout, int last,
                                                  int first) {
    int lane = threadIdx.x & 63;
    int w = threadIdx.x >> 6;
    int m0 = blockIdx.y * 32 + w * 16;
    int n0 = blockIdx.x * 16;
    int lr = lane & 15;
    int kg = lane >> 4;

    f32x4 acc = {};
    if (!first) {
        const f16* arow = hin + (size_t)(m0 + lr) * HB;
        const f16* brow = WhT + (size_t)(n0 + lr) * HB;
#pragma unroll 4
        for (int kk = 0; kk < HB; kk += 32) {
            int k = kk + kg * 8;
            f16x8 a = *reinterpret_cast<const f16x8*>(arow + k);
            f16x8 b = *reinterpret_cast<const f16x8*>(brow + k);
            acc = __builtin_amdgcn_mfma_f32_16x16x32_f16(a, b, acc, 0, 0, 0);
        }
    }

#pragma unroll
    for (int j = 0; j < 4; ++j) {
        int row = m0 + kg * 4 + j;
        int col = n0 + lr;
        float pre = acc[j] + (float)xw_t[(size_t)row * HB + col];
        float h = tanhf(pre);
        hout[(size_t)row * HB + col] = (f16)h;
        if (last) dout[(size_t)row * HB + col] = h;
    }
}

// ---------- phase 2: persistent recurrence, sentinel dataflow (no flags/fences) ----------
// hseq: TT step-indexed buffers, pre-poisoned 0xFF. Step t>0 reads hseq[t-1],
// writes hseq[t] via sc1 fire-and-forget stores. Consumers optimistically load
// and retry any fragment block still containing the 0xFFFF (NaN) sentinel.
__global__ __launch_bounds__(512) void k_rnn_persist(const f16* __restrict__ Wh16T,
                                                     const f16* __restrict__ xw16,
                                                     f16* __restrict__ hseq,
                                                     float* __restrict__ dout) {
    __shared__ float red[64][260];
    int tid = threadIdx.x;
    int lane = tid & 63, w = tid >> 6;
    int lr = lane & 15, kg = lane >> 4;
    int n0 = blockIdx.x * 32;

    f16x8 bfrag[2][8];
#pragma unroll
    for (int ni = 0; ni < 2; ++ni) {
        const f16* brow = Wh16T + (size_t)(n0 + ni * 16 + lr) * HB + w * 256 + kg * 8;
#pragma unroll
        for (int s = 0; s < 8; ++s) bfrag[ni][s] = *(const f16x8*)(brow + s * 32);
    }

    int r_o = tid >> 3;      // 0..63
    int c4 = (tid & 7) * 4;  // 0,4,...,28
    int colbase = n0 + c4;

    for (int t = 0; t < TT; ++t) {
        u64 xwv = *(const u64*)(xw16 + ((size_t)t * BB + r_o) * HB + colbase);

        f32x4 acc[4][2] = {};
        if (t > 0) {
            const f16* rbuf = hseq + (size_t)(t - 1) * BB * HB;
            const f16* abase = rbuf + w * 256 + kg * 8;
            const f16* a0 = abase + (size_t)(0 * 16 + lr) * HB;
            const f16* a1 = abase + (size_t)(1 * 16 + lr) * HB;
            const f16* a2 = abase + (size_t)(2 * 16 + lr) * HB;
            const f16* a3 = abase + (size_t)(3 * 16 + lr) * HB;
            f16x8 hva[8], hvb[8];
            LOADM(hva, a0);
            LOADM(hvb, a1);

            // m=0
            VMCNT(8);
            __builtin_amdgcn_sched_barrier(0);
            {
                int ok = chk8(hva);
                while (!__all(ok)) {
                    __builtin_amdgcn_s_sleep(2);
                    LOADM(hva, a0);
                    VMCNT(0);
                    ok = chk8(hva);
                }
            }
            __builtin_amdgcn_sched_barrier(0);
#pragma unroll
            for (int s = 0; s < 8; ++s) {
                acc[0][0] = __builtin_amdgcn_mfma_f32_16x16x32_f16(hva[s], bfrag[0][s],
                                                                   acc[0][0], 0, 0, 0);
                acc[0][1] = __builtin_amdgcn_mfma_f32_16x16x32_f16(hva[s], bfrag[1][s],
                                                                   acc[0][1], 0, 0, 0);
            }
            LOADM(hva, a2);

            // m=1
            VMCNT(8);
            __builtin_amdgcn_sched_barrier(0);
            {
                int ok = chk8(hvb);
                while (!__all(ok)) {
                    __builtin_amdgcn_s_sleep(2);
                    LOADM(hvb, a1);
                    VMCNT(0);
                    ok = chk8(hvb);
                }
            }
            __builtin_amdgcn_sched_barrier(0);
#pragma unroll
            for (int s = 0; s < 8; ++s) {
                acc[1][0] = __builtin_amdgcn_mfma_f32_16x16x32_f16(hvb[s], bfrag[0][s],
                                                                   acc[1][0], 0, 0, 0);
                acc[1][1] = __builtin_amdgcn_mfma_f32_16x16x32_f16(hvb[s], bfrag[1][s],
                                                                   acc[1][1], 0, 0, 0);
            }
            LOADM(hvb, a3);

            // m=2
            VMCNT(8);
            __builtin_amdgcn_sched_barrier(0);
            {
                int ok = chk8(hva);
                while (!__all(ok)) {
                    __builtin_amdgcn_s_sleep(2);
                    LOADM(hva, a2);
                    VMCNT(0);
                    ok = chk8(hva);
                }
            }
            __builtin_amdgcn_sched_barrier(0);
#pragma unroll
            for (int s = 0; s < 8; ++s) {
                acc[2][0] = __builtin_amdgcn_mfma_f32_16x16x32_f16(hva[s], bfrag[0][s],
                                                                   acc[2][0], 0, 0, 0);
                acc[2][1] = __builtin_amdgcn_mfma_f32_16x16x32_f16(hva[s], bfrag[1][s],
                                                                   acc[2][1], 0, 0, 0);
            }

            // m=3
            VMCNT(0);
            __builtin_amdgcn_sched_barrier(0);
            {
                int ok = chk8(hvb);
                while (!__all(ok)) {
                    __builtin_amdgcn_s_sleep(2);
                    LOADM(hvb, a3);
                    VMCNT(0);
                    ok = chk8(hvb);
                }
            }
            __builtin_amdgcn_sched_barrier(0);
#pragma unroll
            for (int s = 0; s < 8; ++s) {
                acc[3][0] = __builtin_amdgcn_mfma_f32_16x16x32_f16(hvb[s], bfrag[0][s],
                                                                   acc[3][0], 0, 0, 0);
                acc[3][1] = __builtin_amdgcn_mfma_f32_16x16x32_f16(hvb[s], bfrag[1][s],
                                                                   acc[3][1], 0, 0, 0);
            }
        }

        // partials -> LDS: red[row][w*32 + ni*16 + lr]
#pragma unroll
        for (int m = 0; m < 4; ++m)
#pragma unroll
            for (int ni = 0; ni < 2; ++ni) {
                int rbase = m * 16 + kg * 4;
#pragma unroll
                for (int j = 0; j < 4; ++j)
                    red[rbase + j][w * 32 + ni * 16 + lr] = acc[m][ni][j];
            }
        __syncthreads();

        float4 sum = {0.f, 0.f, 0.f, 0.f};
#pragma unroll
        for (int ww = 0; ww < 8; ++ww) {
            float4 v = *(const float4*)&red[r_o][ww * 32 + c4];
            sum.x += v.x; sum.y += v.y; sum.z += v.z; sum.w += v.w;
        }
        union { u64 q; f16 h[4]; } xwu;
        xwu.q = xwv;
        float h0v = tanhf(sum.x + (float)xwu.h[0]);
        float h1v = tanhf(sum.y + (float)xwu.h[1]);
        float h2v = tanhf(sum.z + (float)xwu.h[2]);
        float h3v = tanhf(sum.w + (float)xwu.h[3]);

        if (t == TT - 1) {
            float4 o = {h0v, h1v, h2v, h3v};
            *(float4*)(dout + (size_t)r_o * HB + colbase) = o;
        } else {
            union { u64 q; f16 h[4]; } ho;
            ho.h[0] = (f16)h0v; ho.h[1] = (f16)h1v;
            ho.h[2] = (f16)h2v; ho.h[3] = (f16)h3v;
            // fire-and-forget, write-through to coherence point
            __hip_atomic_store((u64*)(hseq + (size_t)t * BB * HB + (size_t)r_o * HB + colbase),
                               ho.q, __ATOMIC_RELAXED, __HIP_MEMORY_SCOPE_AGENT);
        }
        __syncthreads();  // LDS reuse guard (read -> next write)
    }
}

extern "C" void kernel_launch(void* const* d_in, const int* in_sizes, int n_in,
                              void* d_out, int out_size, void* d_ws, size_t ws_size,
                              hipStream_t stream) {
    const float* x = (const float*)d_in[0];
    const float* W = (const float*)d_in[1];
    const float* Wh = (const float*)d_in[2];
    const float* bias = (const float*)d_in[3];
    float* dout = (float*)d_out;

    char* ws = (char*)d_ws;
    const size_t SZ_WT = (size_t)HB * DD * 2;       // 8 MB
    const size_t SZ_H = (size_t)BB * HB * 2;        // 256 KB
    const size_t SZ_XW = (size_t)TT * BB * HB * 2;  // 64 MB
    const size_t OFF_W = 0;
    const size_t OFF_WH = OFF_W + SZ_WT;
    const size_t OFF_H01 = OFF_WH + SZ_WT;          // fallback ping-pong (2 bufs)
    const size_t OFF_XW = OFF_H01 + 2 * SZ_H;
    const size_t OFF_HSEQ = OFF_XW + SZ_XW;         // doubles as x16 staging
    const size_t NEED_FULL = OFF_HSEQ + SZ_XW;      // TT * 256KB

    f16* W16T = (f16*)(ws + OFF_W);
    f16* Wh16T = (f16*)(ws + OFF_WH);
    f16* h0 = (f16*)(ws + OFF_H01);
    f16* h1 = (f16*)(ws + OFF_H01 + SZ_H);
    f16* xw16 = (f16*)(ws + OFF_XW);
    f16* hseq = (f16*)(ws + OFF_HSEQ);

    dim3 tgrid(32, 32);
    k_transpose_cvt<<<tgrid, 256, 0, stream>>>(W, W16T);
    k_transpose_cvt<<<tgrid, 256, 0, stream>>>(Wh, Wh16T);

    if (ws_size >= NEED_FULL) {
        f16* x16 = hseq;  // staging area, consumed by GEMM, then re-poisoned
        k_cvt_x<<<TT * BB, 256, 0, stream>>>(x, x16);
        k_gemm_xw_lds<<<dim3(HB / 128, TT * BB / 128), 256, 0, stream>>>(x16, W16T, bias, xw16);
        hipMemsetAsync(hseq, 0xFF, SZ_XW, stream);  // sentinel-poison hseq
        k_rnn_persist<<<CWG, 512, 0, stream>>>(Wh16T, xw16, hseq, dout);
    } else {
        k_gemm_xw_direct<<<dim3(HB / 64, TT * BB / 64), 256, 0, stream>>>(x, W16T, bias, xw16);
        f16* hb[2] = {h0, h1};
        for (int t = 0; t < TT; ++t) {
            const f16* xwt = xw16 + (size_t)t * BB * HB;
            k_rnn_step<<<dim3(128, 2), 128, 0, stream>>>(hb[t & 1], Wh16T, xwt,
                                                         hb[(t + 1) & 1], dout,
                                                         t == TT - 1, t == 0);
        }
    }
}